// Round 8
// baseline (1656.945 us; speedup 1.0000x reference)
//
#include <hip/hip_runtime.h>
#include <hip/hip_bf16.h>
#include <math.h>

#define NNODES 20000
#define NEDGES 640000
#define BSZ 256
#define GDIM 256
#define HID 512
#define INNER 2048
#define RANK 512
#define NCLS 3
#define NGENES 6640
#define NBLK 512   // head_k grid: 2 blocks/CU x 256 CUs, guaranteed co-resident

typedef __attribute__((ext_vector_type(8))) short bf16x8;
typedef __attribute__((ext_vector_type(4))) float f32x4;

__device__ inline float bf2f(unsigned short u) {
    return __uint_as_float(((unsigned)u) << 16);
}
__device__ inline unsigned short f2bf(float f) {
    unsigned u = __float_as_uint(f);
    u = u + 0x7fff + ((u >> 16) & 1);   // RNE
    return (unsigned short)(u >> 16);
}

// ---------------- CSR build ----------------
__global__ void hist_k(const int* __restrict__ dst, int* __restrict__ counts, int E) {
    int e = blockIdx.x * 256 + threadIdx.x;
    if (e < E) atomicAdd(&counts[dst[e]], 1);
}

__global__ __launch_bounds__(1024) void scanall_k(const int* __restrict__ counts,
                                                  int* __restrict__ row_start,
                                                  int* __restrict__ cursor, int n) {
    __shared__ int tsum[1024];
    int t = threadIdx.x;
    int base = t * 20;
    int s = 0;
#pragma unroll 4
    for (int i = 0; i < 20; i++) {
        int idx = base + i;
        s += (idx < n) ? counts[idx] : 0;
    }
    tsum[t] = s;
    __syncthreads();
    for (int off = 1; off < 1024; off <<= 1) {
        int v = (t >= off) ? tsum[t - off] : 0;
        __syncthreads();
        tsum[t] += v;
        __syncthreads();
    }
    int run = (t == 0) ? 0 : tsum[t - 1];
    for (int i = 0; i < 20; i++) {
        int idx = base + i;
        if (idx < n) {
            row_start[idx] = run;
            cursor[idx] = run;
            run += counts[idx];
        }
    }
}

__global__ void scatter_k(const int* __restrict__ src, const int* __restrict__ dst,
                          const float* __restrict__ w, int* __restrict__ cursor,
                          int2* __restrict__ ep, int E) {
    int e = blockIdx.x * 256 + threadIdx.x;
    if (e < E) {
        int d = dst[e];
        int p = atomicAdd(&cursor[d], 1);
        ep[p] = make_int2(src[e], __float_as_int(w[e]));
    }
}

// ---------------- mega conversion kernel ----------------
__global__ void convall_k(const float* __restrict__ gnn_w, const float* __restrict__ post_w,
                          const float* __restrict__ pin_w, const float* __restrict__ blk_w1,
                          const float* __restrict__ blk_w2, const float* __restrict__ pout_w,
                          const float* __restrict__ gene, unsigned short* __restrict__ gnnT,
                          unsigned short* __restrict__ postT, unsigned short* __restrict__ pinT,
                          unsigned short* __restrict__ w1T, unsigned short* __restrict__ w2T,
                          unsigned short* __restrict__ poutT,
                          unsigned short* __restrict__ geneb) {
    __shared__ float s[32][33];
    int bid = blockIdx.x;
    int tx = threadIdx.x, ty = threadIdx.y;
    const float* W;
    unsigned short* WT;
    int K, N, k0, n0;
    if (bid < 192) {
        int l = bid >> 6, rem = bid & 63;
        W = gnn_w + (size_t)l * GDIM * GDIM;
        WT = gnnT + (size_t)l * GDIM * GDIM;
        K = GDIM; N = GDIM;
        n0 = (rem & 7) * 32; k0 = (rem >> 3) * 32;
    } else if (bid < 256) {
        int rem = bid - 192;
        W = post_w; WT = postT; K = GDIM; N = GDIM;
        n0 = (rem & 7) * 32; k0 = (rem >> 3) * 32;
    } else if (bid < 384) {
        int rem = bid - 256;
        W = pin_w; WT = pinT; K = GDIM; N = HID;
        n0 = (rem & 15) * 32; k0 = (rem >> 4) * 32;
    } else if (bid < 6528) {
        int rem = bid - 384;
        int l = rem >> 10; rem &= 1023;
        W = blk_w1 + (size_t)l * HID * INNER;
        WT = w1T + (size_t)l * HID * INNER;
        K = HID; N = INNER;
        n0 = (rem & 63) * 32; k0 = (rem >> 6) * 32;
    } else if (bid < 12672) {
        int rem = bid - 6528;
        int l = rem >> 10; rem &= 1023;
        W = blk_w2 + (size_t)l * INNER * HID;
        WT = w2T + (size_t)l * INNER * HID;
        K = INNER; N = HID;
        n0 = (rem & 15) * 32; k0 = (rem >> 4) * 32;
    } else if (bid < 13440) {
        int rem = bid - 12672;
        W = pout_w; WT = poutT; K = HID; N = NCLS * RANK;
        n0 = (rem % 48) * 32; k0 = (rem / 48) * 32;
    } else {
        int i8 = (bid - 13440) * 256 + ty * 32 + tx;
        const float4* xp = (const float4*)gene;
        float4 a = xp[i8 * 2], b = xp[i8 * 2 + 1];
        *(ushort4*)(geneb + (size_t)i8 * 8) =
            make_ushort4(f2bf(a.x), f2bf(a.y), f2bf(a.z), f2bf(a.w));
        *(ushort4*)(geneb + (size_t)i8 * 8 + 4) =
            make_ushort4(f2bf(b.x), f2bf(b.y), f2bf(b.z), f2bf(b.w));
        return;
    }
#pragma unroll
    for (int i = 0; i < 4; i++)
        s[ty + 8 * i][tx] = W[(size_t)(k0 + ty + 8 * i) * N + n0 + tx];
    __syncthreads();
#pragma unroll
    for (int i = 0; i < 4; i++)
        WT[(size_t)(n0 + ty + 8 * i) * K + k0 + tx] = f2bf(s[tx][ty + 8 * i]);
}

// ---------------- GNN LayerNorm (D=256), bf16 out ----------------
__global__ void lnb_k(const float* __restrict__ X, const float* __restrict__ sc,
                      const float* __restrict__ bi, unsigned short* __restrict__ Y, int M) {
    int row = blockIdx.x * 4 + (threadIdx.x >> 6);
    int lane = threadIdx.x & 63;
    if (row >= M) return;
    float4 v = ((const float4*)(X + (size_t)row * GDIM))[lane];
    float sum = v.x + v.y + v.z + v.w;
#pragma unroll
    for (int off = 32; off >= 1; off >>= 1) sum += __shfl_xor(sum, off);
    float mu = sum / GDIM;
    float a = v.x - mu, b = v.y - mu, c = v.z - mu, d = v.w - mu;
    float sq = a * a + b * b + c * c + d * d;
#pragma unroll
    for (int off = 32; off >= 1; off >>= 1) sq += __shfl_xor(sq, off);
    float rstd = rsqrtf(sq / GDIM + 1e-5f);
    float4 s4 = ((const float4*)sc)[lane];
    float4 b4 = ((const float4*)bi)[lane];
    *(ushort4*)(Y + (size_t)row * GDIM + lane * 4) =
        make_ushort4(f2bf(a * rstd * s4.x + b4.x), f2bf(b * rstd * s4.y + b4.y),
                     f2bf(c * rstd * s4.z + b4.z), f2bf(d * rstd * s4.w + b4.w));
}

// ---------------- CSR aggregation ----------------
__device__ inline void agg_row(int beg, int cnt, int lane, const int2* __restrict__ ep,
                               const unsigned short* __restrict__ H, float& a0, float& a1,
                               float& a2, float& a3) {
    int t = 0;
    for (; t + 16 <= cnt; t += 16) {
        int2 e[16];
#pragma unroll
        for (int u = 0; u < 16; u++) e[u] = ep[beg + t + u];
        ushort4 v[16];
#pragma unroll
        for (int u = 0; u < 16; u++)
            v[u] = *(const ushort4*)(H + (size_t)e[u].x * GDIM + lane * 4);
#pragma unroll
        for (int u = 0; u < 16; u++) {
            float w = __int_as_float(e[u].y);
            a0 = fmaf(bf2f(v[u].x), w, a0);
            a1 = fmaf(bf2f(v[u].y), w, a1);
            a2 = fmaf(bf2f(v[u].z), w, a2);
            a3 = fmaf(bf2f(v[u].w), w, a3);
        }
    }
    for (; t + 4 <= cnt; t += 4) {
        int2 e[4];
#pragma unroll
        for (int u = 0; u < 4; u++) e[u] = ep[beg + t + u];
        ushort4 v[4];
#pragma unroll
        for (int u = 0; u < 4; u++)
            v[u] = *(const ushort4*)(H + (size_t)e[u].x * GDIM + lane * 4);
#pragma unroll
        for (int u = 0; u < 4; u++) {
            float w = __int_as_float(e[u].y);
            a0 = fmaf(bf2f(v[u].x), w, a0);
            a1 = fmaf(bf2f(v[u].y), w, a1);
            a2 = fmaf(bf2f(v[u].z), w, a2);
            a3 = fmaf(bf2f(v[u].w), w, a3);
        }
    }
    for (; t < cnt; t++) {
        int2 e = ep[beg + t];
        float w = __int_as_float(e.y);
        ushort4 v = *(const ushort4*)(H + (size_t)e.x * GDIM + lane * 4);
        a0 = fmaf(bf2f(v.x), w, a0);
        a1 = fmaf(bf2f(v.y), w, a1);
        a2 = fmaf(bf2f(v.z), w, a2);
        a3 = fmaf(bf2f(v.w), w, a3);
    }
}

__global__ void aggb_k(const int* __restrict__ row_start, const int* __restrict__ counts,
                       const int2* __restrict__ ep, const unsigned short* __restrict__ H,
                       unsigned short* __restrict__ AGG, int n) {
    int row = blockIdx.x * 4 + (threadIdx.x >> 6);
    int lane = threadIdx.x & 63;
    if (row >= n) return;
    float a0 = 0.f, a1 = 0.f, a2 = 0.f, a3 = 0.f;
    agg_row(row_start[row], counts[row], lane, ep, H, a0, a1, a2, a3);
    *(ushort4*)(AGG + (size_t)row * GDIM + lane * 4) =
        make_ushort4(f2bf(a0), f2bf(a1), f2bf(a2), f2bf(a3));
}

// ---------------- GNN GEMM 128x128 (fp32 out, relu+bias+residual) ----------------
template <int ACT, bool RES, bool BIAS>
__global__ __launch_bounds__(256) void mgemm_k(const unsigned short* __restrict__ A,
                                               const unsigned short* __restrict__ BT,
                                               const float* __restrict__ bias,
                                               const float* __restrict__ R,
                                               float* __restrict__ C, int M, int N, int K) {
    __shared__ unsigned short As[128 * 32];
    __shared__ unsigned short Bs[128 * 32];
    int m0 = blockIdx.y * 128, n0 = blockIdx.x * 128;
    int tid = threadIdx.x;
    int wave = tid >> 6, lane = tid & 63;
    int wm = (wave >> 1) * 64, wn = (wave & 1) * 64;
    int lrow = lane & 15, lq = lane >> 4;

    f32x4 acc[4][4];
    const f32x4 zz = {0.f, 0.f, 0.f, 0.f};
#pragma unroll
    for (int i = 0; i < 4; i++)
#pragma unroll
        for (int j = 0; j < 4; j++) acc[i][j] = zz;

    int r0 = tid >> 2;
    int q = tid & 3;

    for (int k0 = 0; k0 < K; k0 += 32) {
#pragma unroll
        for (int p = 0; p < 2; p++) {
            int row = r0 + p * 64;
            int gm = m0 + row;
            uint4 va = make_uint4(0, 0, 0, 0);
            if (gm < M) va = *(const uint4*)(A + (size_t)gm * K + k0 + q * 8);
            *(uint4*)&As[row * 32 + q * 8] = va;
            int gn = n0 + row;
            uint4 vb = make_uint4(0, 0, 0, 0);
            if (gn < N) vb = *(const uint4*)(BT + (size_t)gn * K + k0 + q * 8);
            *(uint4*)&Bs[row * 32 + q * 8] = vb;
        }
        __syncthreads();
        bf16x8 af[4], bfr[4];
#pragma unroll
        for (int i = 0; i < 4; i++)
            af[i] = *(const bf16x8*)&As[(wm + i * 16 + lrow) * 32 + lq * 8];
#pragma unroll
        for (int j = 0; j < 4; j++)
            bfr[j] = *(const bf16x8*)&Bs[(wn + j * 16 + lrow) * 32 + lq * 8];
#pragma unroll
        for (int i = 0; i < 4; i++)
#pragma unroll
            for (int j = 0; j < 4; j++)
                acc[i][j] =
                    __builtin_amdgcn_mfma_f32_16x16x32_bf16(af[i], bfr[j], acc[i][j], 0, 0, 0);
        __syncthreads();
    }

#pragma unroll
    for (int i = 0; i < 4; i++) {
#pragma unroll
        for (int j = 0; j < 4; j++) {
            int gn = n0 + wn + j * 16 + lrow;
            if (gn >= N) continue;
            float bv = BIAS ? bias[gn] : 0.f;
#pragma unroll
            for (int r = 0; r < 4; r++) {
                int gm = m0 + wm + i * 16 + lq * 4 + r;
                if (gm >= M) continue;
                float v = acc[i][j][r] + bv;
                if (ACT == 1) v = fmaxf(v, 0.f);
                if (RES) v += R[(size_t)gm * N + gn];
                C[(size_t)gm * N + gn] = v;
            }
        }
    }
}

// ---------------- persistent head kernel ----------------
// 512 blocks x 256 threads, co-resident (2/CU). Manual grid barrier.
__device__ inline void gbar(int* bar, int& bt) {
    bt += NBLK;
    __syncthreads();
    if (threadIdx.x == 0) {
        __threadfence();                 // wb L2 -> LLC (release)
        atomicAdd(bar, 1);
        while (atomicAdd(bar, 0) < bt)   // poll at LLC coherence point
            __builtin_amdgcn_s_sleep(1);
        __threadfence();                 // invalidate stale L1/L2 (acquire)
    }
    __syncthreads();
}

// wave-level 16x64 sub-GEMM; whole block stages a 64x64 A/BT tile per k-step
__device__ inline void g64(const unsigned short* __restrict__ A,
                           const unsigned short* __restrict__ BT, int K, int kbeg, int kend,
                           int m0, int n0, unsigned short* As, unsigned short* Bs, f32x4 acc[4],
                           int tid) {
    int wave = tid >> 6, lane = tid & 63;
    int wm = wave * 16, lrow = lane & 15, lq = lane >> 4;
    int r0 = tid >> 2, q = tid & 3;
    for (int k0 = kbeg; k0 < kend; k0 += 32) {
        *(uint4*)&As[r0 * 32 + q * 8] = *(const uint4*)(A + (size_t)(m0 + r0) * K + k0 + q * 8);
        *(uint4*)&Bs[r0 * 32 + q * 8] = *(const uint4*)(BT + (size_t)(n0 + r0) * K + k0 + q * 8);
        __syncthreads();
        bf16x8 af = *(const bf16x8*)&As[(wm + lrow) * 32 + lq * 8];
#pragma unroll
        for (int j = 0; j < 4; j++) {
            bf16x8 bfr = *(const bf16x8*)&Bs[(j * 16 + lrow) * 32 + lq * 8];
            acc[j] = __builtin_amdgcn_mfma_f32_16x16x32_bf16(af, bfr, acc[j], 0, 0, 0);
        }
        __syncthreads();
    }
}

__global__ __launch_bounds__(256, 2) void head_k(
    const int* __restrict__ node_indices, const int* __restrict__ row_start,
    const int* __restrict__ counts, const int2* __restrict__ ep,
    const unsigned short* __restrict__ ln_bf, const float* __restrict__ xb,
    const unsigned short* __restrict__ gnnT3, const float* __restrict__ gnn_b3,
    const unsigned short* __restrict__ postT, const float* __restrict__ post_b,
    const float* __restrict__ oov_emb, const unsigned short* __restrict__ pinT,
    const float* __restrict__ pin_b, const float* __restrict__ blk_ln_s,
    const float* __restrict__ blk_ln_b, const unsigned short* __restrict__ w1T,
    const float* __restrict__ blk_b1, const unsigned short* __restrict__ w2T,
    const float* __restrict__ blk_b2, const unsigned short* __restrict__ poutT,
    const float* __restrict__ pout_b, const unsigned short* __restrict__ geneb,
    float* __restrict__ out, unsigned short* __restrict__ aggselb,
    unsigned short* __restrict__ pertinbf, unsigned short* __restrict__ pertbf,
    float* __restrict__ hbuf, unsigned short* __restrict__ zlnbf,
    unsigned short* __restrict__ z1bf, unsigned short* __restrict__ hbufbf,
    unsigned short* __restrict__ projb, float* __restrict__ partH, int* bar) {
    __shared__ unsigned short As[128 * 32];
    __shared__ unsigned short Bs[128 * 32];
    int bid = blockIdx.x;
    int tid = threadIdx.x;
    int wave = tid >> 6, lane = tid & 63;
    int lrow = lane & 15, lq = lane >> 4;
    int bt = 0;
    const f32x4 zz = {0.f, 0.f, 0.f, 0.f};

    // SA: layer-3 selective aggregation (256 rows, wave per row)
    if (bid < 64) {
        int b = bid * 4 + wave;
        int id = node_indices[b];
        int row = id < 0 ? 0 : id;
        float a0 = 0.f, a1 = 0.f, a2 = 0.f, a3 = 0.f;
        agg_row(row_start[row], counts[row], lane, ep, ln_bf, a0, a1, a2, a3);
        *(ushort4*)(aggselb + (size_t)b * GDIM + lane * 4) =
            make_ushort4(f2bf(a0), f2bf(a1), f2bf(a2), f2bf(a3));
    }
    gbar(bar, bt);

    // SB: layer-3 GEMM: relu(aggsel@W3+b3) + xb[idx] -> pertinbf (16 tiles)
    if (bid < 16) {
        int m0 = (bid & 3) * 64, n0 = (bid >> 2) * 64;
        f32x4 acc[4];
#pragma unroll
        for (int j = 0; j < 4; j++) acc[j] = zz;
        g64(aggselb, gnnT3, GDIM, 0, GDIM, m0, n0, As, Bs, acc, tid);
#pragma unroll
        for (int j = 0; j < 4; j++) {
            int gn = n0 + j * 16 + lrow;
            float bv = gnn_b3[gn];
#pragma unroll
            for (int r = 0; r < 4; r++) {
                int gm = m0 + wave * 16 + lq * 4 + r;
                float v = fmaxf(acc[j][r] + bv, 0.f);
                int id = node_indices[gm];
                int safe = id < 0 ? 0 : id;
                v += xb[(size_t)safe * GDIM + gn];
                pertinbf[(size_t)gm * GDIM + gn] = f2bf(v);
            }
        }
    }
    gbar(bar, bt);

    // SC: post_mp + OOV replace -> pertbf (16 tiles)
    if (bid < 16) {
        int m0 = (bid & 3) * 64, n0 = (bid >> 2) * 64;
        f32x4 acc[4];
#pragma unroll
        for (int j = 0; j < 4; j++) acc[j] = zz;
        g64(pertinbf, postT, GDIM, 0, GDIM, m0, n0, As, Bs, acc, tid);
#pragma unroll
        for (int j = 0; j < 4; j++) {
            int gn = n0 + j * 16 + lrow;
            float bv = post_b[gn];
#pragma unroll
            for (int r = 0; r < 4; r++) {
                int gm = m0 + wave * 16 + lq * 4 + r;
                float v = acc[j][r] + bv;
                if (node_indices[gm] < 0) v = oov_emb[gn];
                pertbf[(size_t)gm * GDIM + gn] = f2bf(v);
            }
        }
    }
    gbar(bar, bt);

    // S0: pin GEMM -> hbuf fp32 (+bias), 32 tiles
    if (bid < 32) {
        int m0 = (bid & 3) * 64, n0 = (bid >> 2) * 64;
        f32x4 acc[4];
#pragma unroll
        for (int j = 0; j < 4; j++) acc[j] = zz;
        g64(pertbf, pinT, GDIM, 0, GDIM, m0, n0, As, Bs, acc, tid);
#pragma unroll
        for (int j = 0; j < 4; j++) {
            int gn = n0 + j * 16 + lrow;
            float bv = pin_b[gn];
#pragma unroll
            for (int r = 0; r < 4; r++) {
                int gm = m0 + wave * 16 + lq * 4 + r;
                hbuf[(size_t)gm * HID + gn] = acc[j][r] + bv;
            }
        }
    }
    gbar(bar, bt);

    // S1: LN(hbuf) -> zlnbf  (block-0 LN params)
    if (bid < 64) {
        int row = bid * 4 + wave;
        const float4* hp = (const float4*)(hbuf + (size_t)row * HID);
        float4 a0 = hp[lane * 2], a1 = hp[lane * 2 + 1];
        float sum = a0.x + a0.y + a0.z + a0.w + a1.x + a1.y + a1.z + a1.w;
#pragma unroll
        for (int off = 32; off >= 1; off >>= 1) sum += __shfl_xor(sum, off);
        float mu = sum / HID;
        float d0 = a0.x - mu, d1 = a0.y - mu, d2 = a0.z - mu, d3 = a0.w - mu;
        float d4 = a1.x - mu, d5 = a1.y - mu, d6 = a1.z - mu, d7 = a1.w - mu;
        float sq = d0 * d0 + d1 * d1 + d2 * d2 + d3 * d3 + d4 * d4 + d5 * d5 + d6 * d6 + d7 * d7;
#pragma unroll
        for (int off = 32; off >= 1; off >>= 1) sq += __shfl_xor(sq, off);
        float rstd = rsqrtf(sq / HID + 1e-5f);
        const float4* sp = (const float4*)blk_ln_s;
        const float4* bp = (const float4*)blk_ln_b;
        float4 s0 = sp[lane * 2], s1 = sp[lane * 2 + 1];
        float4 t0 = bp[lane * 2], t1 = bp[lane * 2 + 1];
        unsigned short* op = zlnbf + (size_t)row * HID;
        *(ushort4*)(op + lane * 8) =
            make_ushort4(f2bf(d0 * rstd * s0.x + t0.x), f2bf(d1 * rstd * s0.y + t0.y),
                         f2bf(d2 * rstd * s0.z + t0.z), f2bf(d3 * rstd * s0.w + t0.w));
        *(ushort4*)(op + lane * 8 + 4) =
            make_ushort4(f2bf(d4 * rstd * s1.x + t1.x), f2bf(d5 * rstd * s1.y + t1.y),
                         f2bf(d6 * rstd * s1.z + t1.z), f2bf(d7 * rstd * s1.w + t1.w));
    }
    gbar(bar, bt);

    // 6 head blocks
    for (int i = 0; i < 6; i++) {
        // S2: w1 + gelu -> z1bf (128 tiles)
        if (bid < 128) {
            int m0 = (bid & 3) * 64, n0 = (bid >> 2) * 64;
            f32x4 acc[4];
#pragma unroll
            for (int j = 0; j < 4; j++) acc[j] = zz;
            g64(zlnbf, w1T + (size_t)i * INNER * HID, HID, 0, HID, m0, n0, As, Bs, acc, tid);
            const float* b1 = blk_b1 + i * INNER;
#pragma unroll
            for (int j = 0; j < 4; j++) {
                int gn = n0 + j * 16 + lrow;
                float bv = b1[gn];
#pragma unroll
                for (int r = 0; r < 4; r++) {
                    int gm = m0 + wave * 16 + lq * 4 + r;
                    float v = acc[j][r] + bv;
                    v = 0.5f * v * (1.f + erff(v * 0.70710678118654752f));
                    z1bf[(size_t)gm * INNER + gn] = f2bf(v);
                }
            }
        }
        gbar(bar, bt);

        // S3: w2 split-K S=8 -> partH (256 jobs)
        if (bid < 256) {
            int s = bid >> 5, t = bid & 31;
            int m0 = (t & 3) * 64, n0 = (t >> 2) * 64;
            f32x4 acc[4];
#pragma unroll
            for (int j = 0; j < 4; j++) acc[j] = zz;
            g64(z1bf, w2T + (size_t)i * HID * INNER, INNER, s * 256, s * 256 + 256, m0, n0, As,
                Bs, acc, tid);
            float* C = partH + (size_t)s * BSZ * HID;
#pragma unroll
            for (int j = 0; j < 4; j++) {
                int gn = n0 + j * 16 + lrow;
#pragma unroll
                for (int r = 0; r < 4; r++) {
                    int gm = m0 + wave * 16 + lq * 4 + r;
                    C[(size_t)gm * HID + gn] = acc[j][r];
                }
            }
        }
        gbar(bar, bt);

        // S4: reduce + bias + residual -> hbuf; LN -> zlnbf (i<5) or plain -> hbufbf
        if (bid < 64) {
            int row = bid * 4 + wave;
            float4 a0 = {0.f, 0.f, 0.f, 0.f}, a1 = a0;
            for (int s = 0; s < 8; s++) {
                const float4* pp = (const float4*)(partH + ((size_t)s * BSZ + row) * HID);
                float4 b0 = pp[lane * 2], b1v = pp[lane * 2 + 1];
                a0.x += b0.x; a0.y += b0.y; a0.z += b0.z; a0.w += b0.w;
                a1.x += b1v.x; a1.y += b1v.y; a1.z += b1v.z; a1.w += b1v.w;
            }
            const float4* bb = (const float4*)(blk_b2 + i * HID);
            float4 c0 = bb[lane * 2], c1 = bb[lane * 2 + 1];
            a0.x += c0.x; a0.y += c0.y; a0.z += c0.z; a0.w += c0.w;
            a1.x += c1.x; a1.y += c1.y; a1.z += c1.z; a1.w += c1.w;
            float4* hp = (float4*)(hbuf + (size_t)row * HID);
            float4 r0v = hp[lane * 2], r1v = hp[lane * 2 + 1];
            a0.x += r0v.x; a0.y += r0v.y; a0.z += r0v.z; a0.w += r0v.w;
            a1.x += r1v.x; a1.y += r1v.y; a1.z += r1v.z; a1.w += r1v.w;
            hp[lane * 2] = a0;
            hp[lane * 2 + 1] = a1;
            if (i < 5) {
                float sum = a0.x + a0.y + a0.z + a0.w + a1.x + a1.y + a1.z + a1.w;
#pragma unroll
                for (int off = 32; off >= 1; off >>= 1) sum += __shfl_xor(sum, off);
                float mu = sum / HID;
                float d0 = a0.x - mu, d1 = a0.y - mu, d2 = a0.z - mu, d3 = a0.w - mu;
                float d4 = a1.x - mu, d5 = a1.y - mu, d6 = a1.z - mu, d7 = a1.w - mu;
                float sq = d0 * d0 + d1 * d1 + d2 * d2 + d3 * d3 + d4 * d4 + d5 * d5 +
                           d6 * d6 + d7 * d7;
#pragma unroll
                for (int off = 32; off >= 1; off >>= 1) sq += __shfl_xor(sq, off);
                float rstd = rsqrtf(sq / HID + 1e-5f);
                const float4* sp = (const float4*)(blk_ln_s + (i + 1) * HID);
                const float4* bp = (const float4*)(blk_ln_b + (i + 1) * HID);
                float4 s0 = sp[lane * 2], s1 = sp[lane * 2 + 1];
                float4 t0 = bp[lane * 2], t1 = bp[lane * 2 + 1];
                unsigned short* op = zlnbf + (size_t)row * HID;
                *(ushort4*)(op + lane * 8) =
                    make_ushort4(f2bf(d0 * rstd * s0.x + t0.x), f2bf(d1 * rstd * s0.y + t0.y),
                                 f2bf(d2 * rstd * s0.z + t0.z), f2bf(d3 * rstd * s0.w + t0.w));
                *(ushort4*)(op + lane * 8 + 4) =
                    make_ushort4(f2bf(d4 * rstd * s1.x + t1.x), f2bf(d5 * rstd * s1.y + t1.y),
                                 f2bf(d6 * rstd * s1.z + t1.z), f2bf(d7 * rstd * s1.w + t1.w));
            } else {
                unsigned short* op = hbufbf + (size_t)row * HID;
                *(ushort4*)(op + lane * 8) =
                    make_ushort4(f2bf(a0.x), f2bf(a0.y), f2bf(a0.z), f2bf(a0.w));
                *(ushort4*)(op + lane * 8 + 4) =
                    make_ushort4(f2bf(a1.x), f2bf(a1.y), f2bf(a1.z), f2bf(a1.w));
            }
        }
        gbar(bar, bt);
    }

    // S5: pout -> projb (96 tiles)
    if (bid < 96) {
        int m0 = (bid & 3) * 64, n0 = (bid >> 2) * 64;
        f32x4 acc[4];
#pragma unroll
        for (int j = 0; j < 4; j++) acc[j] = zz;
        g64(hbufbf, poutT, HID, 0, HID, m0, n0, As, Bs, acc, tid);
#pragma unroll
        for (int j = 0; j < 4; j++) {
            int gn = n0 + j * 16 + lrow;
            float bv = pout_b[gn];
#pragma unroll
            for (int r = 0; r < 4; r++) {
                int gm = m0 + wave * 16 + lq * 4 + r;
                projb[(size_t)gm * (NCLS * RANK) + gn] = f2bf(acc[j][r] + bv);
            }
        }
    }
    gbar(bar, bt);

    // S6: logits 128x128 tiles (312 jobs)
    if (bid < 312) {
        int mrow = bid % 6, ncol = bid / 6;
        int m0 = mrow * 128, n0 = ncol * 128;
        int wm = (wave >> 1) * 64, wn = (wave & 1) * 64;
        f32x4 acc[4][4];
#pragma unroll
        for (int ii = 0; ii < 4; ii++)
#pragma unroll
            for (int j = 0; j < 4; j++) acc[ii][j] = zz;
        int r0 = tid >> 2;
        int q = tid & 3;
        for (int k0 = 0; k0 < RANK; k0 += 32) {
#pragma unroll
            for (int pp = 0; pp < 2; pp++) {
                int row = r0 + pp * 64;
                *(uint4*)&As[row * 32 + q * 8] =
                    *(const uint4*)(projb + (size_t)(m0 + row) * RANK + k0 + q * 8);
                int gn = n0 + row;
                uint4 vb = make_uint4(0, 0, 0, 0);
                if (gn < NGENES) vb = *(const uint4*)(geneb + (size_t)gn * RANK + k0 + q * 8);
                *(uint4*)&Bs[row * 32 + q * 8] = vb;
            }
            __syncthreads();
            bf16x8 af[4], bfr[4];
#pragma unroll
            for (int ii = 0; ii < 4; ii++)
                af[ii] = *(const bf16x8*)&As[(wm + ii * 16 + lrow) * 32 + lq * 8];
#pragma unroll
            for (int j = 0; j < 4; j++)
                bfr[j] = *(const bf16x8*)&Bs[(wn + j * 16 + lrow) * 32 + lq * 8];
#pragma unroll
            for (int ii = 0; ii < 4; ii++)
#pragma unroll
                for (int j = 0; j < 4; j++)
                    acc[ii][j] = __builtin_amdgcn_mfma_f32_16x16x32_bf16(af[ii], bfr[j],
                                                                          acc[ii][j], 0, 0, 0);
            __syncthreads();
        }
#pragma unroll
        for (int ii = 0; ii < 4; ii++) {
#pragma unroll
            for (int j = 0; j < 4; j++) {
                int gn = n0 + wn + j * 16 + lrow;
                if (gn >= NGENES) continue;
#pragma unroll
                for (int r = 0; r < 4; r++) {
                    int gm = m0 + wm + ii * 16 + lq * 4 + r;
                    out[(size_t)gm * NGENES + gn] = acc[ii][j][r];
                }
            }
        }
    }
}

// ---------------- launch ----------------
extern "C" void kernel_launch(void* const* d_in, const int* in_sizes, int n_in,
                              void* d_out, int out_size, void* d_ws, size_t ws_size,
                              hipStream_t stream) {
    const int* node_indices = (const int*)d_in[0];
    const int* edge_src = (const int*)d_in[1];
    const int* edge_dst = edge_src + NEDGES;
    const float* edge_w = (const float*)d_in[2];
    const float* partial_emb = (const float*)d_in[3];
    const float* oov_emb = (const float*)d_in[4];
    const float* gnn_ln_s = (const float*)d_in[5];
    const float* gnn_ln_b = (const float*)d_in[6];
    const float* gnn_w = (const float*)d_in[7];
    const float* gnn_b = (const float*)d_in[8];
    const float* post_w = (const float*)d_in[9];
    const float* post_b = (const float*)d_in[10];
    const float* pin_w = (const float*)d_in[11];
    const float* pin_b = (const float*)d_in[12];
    const float* blk_ln_s = (const float*)d_in[13];
    const float* blk_ln_b = (const float*)d_in[14];
    const float* blk_w1 = (const float*)d_in[15];
    const float* blk_b1 = (const float*)d_in[16];
    const float* blk_w2 = (const float*)d_in[17];
    const float* blk_b2 = (const float*)d_in[18];
    const float* pout_w = (const float*)d_in[19];
    const float* pout_b = (const float*)d_in[20];
    const float* gene = (const float*)d_in[21];
    float* out = (float*)d_out;

    char* p = (char*)d_ws;
    auto alloc = [&](size_t bytes) {
        char* r = p;
        p += (bytes + 255) & ~(size_t)255;
        return r;
    };
    int* counts = (int*)alloc(NNODES * 4 + 256);   // + barrier counter region
    int* bar = counts + NNODES;
    int* row_start = (int*)alloc(NNODES * 4);
    int* cursor = (int*)alloc(NNODES * 4);
    int2* epack = (int2*)alloc((size_t)NEDGES * 8);
    float* part = (float*)alloc((size_t)NNODES * GDIM * 4);   // GNN: ln_bf + aggbf
    unsigned short* ln_bf = (unsigned short*)part;
    unsigned short* aggbf = (unsigned short*)((char*)part + (size_t)NNODES * GDIM * 2);
    float* partH = (float*)alloc((size_t)8 * BSZ * HID * 4);  // head split-K partials (4 MB)
    float* xa = (float*)alloc((size_t)NNODES * GDIM * 4);
    float* xb = (float*)alloc((size_t)NNODES * GDIM * 4);
    float* hbuf = (float*)alloc((size_t)BSZ * HID * 4);
    unsigned short* aggselb = (unsigned short*)alloc((size_t)BSZ * GDIM * 2);
    unsigned short* pertinbf = (unsigned short*)alloc((size_t)BSZ * GDIM * 2);
    unsigned short* pertbf = (unsigned short*)alloc((size_t)BSZ * GDIM * 2);
    unsigned short* zlnbf = (unsigned short*)alloc((size_t)BSZ * HID * 2);
    unsigned short* z1bf = (unsigned short*)alloc((size_t)BSZ * INNER * 2);
    unsigned short* hbufbf = (unsigned short*)alloc((size_t)BSZ * HID * 2);
    unsigned short* projb = (unsigned short*)alloc((size_t)BSZ * NCLS * RANK * 2);
    unsigned short* gnnT = (unsigned short*)alloc((size_t)3 * GDIM * GDIM * 2);
    unsigned short* postT = (unsigned short*)alloc((size_t)GDIM * GDIM * 2);
    unsigned short* pinT = (unsigned short*)alloc((size_t)HID * GDIM * 2);
    unsigned short* w1T = (unsigned short*)alloc((size_t)6 * INNER * HID * 2);
    unsigned short* w2T = (unsigned short*)alloc((size_t)6 * HID * INNER * 2);
    unsigned short* poutT = (unsigned short*)alloc((size_t)NCLS * RANK * HID * 2);
    unsigned short* geneb = (unsigned short*)alloc((size_t)NGENES * RANK * 2);

    const int EB = (NEDGES + 255) / 256;

    hipMemsetAsync(counts, 0, NNODES * 4 + 256, stream);
    convall_k<<<15100, dim3(32, 8), 0, stream>>>(gnn_w, post_w, pin_w, blk_w1, blk_w2, pout_w,
                                                 gene, gnnT, postT, pinT, w1T, w2T, poutT, geneb);

    // CSR build
    hist_k<<<EB, 256, 0, stream>>>(edge_dst, counts, NEDGES);
    scanall_k<<<1, 1024, 0, stream>>>(counts, row_start, cursor, NNODES);
    scatter_k<<<EB, 256, 0, stream>>>(edge_src, edge_dst, edge_w, cursor, epack, NEDGES);

    // GNN layers 1 & 2 (full graph), separate LN (parallelism) + 128x128 GEMM
    lnb_k<<<(NNODES + 3) / 4, 256, 0, stream>>>(partial_emb, gnn_ln_s, gnn_ln_b, ln_bf, NNODES);
    aggb_k<<<(NNODES + 3) / 4, 256, 0, stream>>>(row_start, counts, epack, ln_bf, aggbf, NNODES);
    mgemm_k<1, true, true><<<dim3(GDIM / 128, (NNODES + 127) / 128), 256, 0, stream>>>(
        aggbf, gnnT, gnn_b, partial_emb, xa, NNODES, GDIM, GDIM);
    lnb_k<<<(NNODES + 3) / 4, 256, 0, stream>>>(xa, gnn_ln_s + GDIM, gnn_ln_b + GDIM, ln_bf,
                                                NNODES);
    aggb_k<<<(NNODES + 3) / 4, 256, 0, stream>>>(row_start, counts, epack, ln_bf, aggbf, NNODES);
    mgemm_k<1, true, true><<<dim3(GDIM / 128, (NNODES + 127) / 128), 256, 0, stream>>>(
        aggbf, gnnT + (size_t)GDIM * GDIM, gnn_b + GDIM, xa, xb, NNODES, GDIM, GDIM);
    lnb_k<<<(NNODES + 3) / 4, 256, 0, stream>>>(xb, gnn_ln_s + 2 * GDIM, gnn_ln_b + 2 * GDIM,
                                                ln_bf, NNODES);

    // persistent head kernel: aggsel -> L3 -> post -> pin -> 6 blocks -> pout -> logits
    head_k<<<NBLK, 256, 0, stream>>>(
        node_indices, row_start, counts, epack, ln_bf, xb, gnnT + (size_t)2 * GDIM * GDIM,
        gnn_b + 2 * GDIM, postT, post_b, oov_emb, pinT, pin_b, blk_ln_s, blk_ln_b, w1T, blk_b1,
        w2T, blk_b2, poutT, pout_b, geneb, out, aggselb, pertinbf, pertbf, hbuf, zlnbf, z1bf,
        hbufbf, projb, partH, bar);
}

// Round 9
// 625.988 us; speedup vs baseline: 2.6469x; 2.6469x over previous
//
#include <hip/hip_runtime.h>
#include <hip/hip_bf16.h>
#include <math.h>

#define NNODES 20000
#define NEDGES 640000
#define BSZ 256
#define GDIM 256
#define HID 512
#define INNER 2048
#define RANK 512
#define NCLS 3
#define NGENES 6640

typedef __attribute__((ext_vector_type(8))) short bf16x8;
typedef __attribute__((ext_vector_type(4))) float f32x4;

__device__ inline float bf2f(unsigned short u) {
    return __uint_as_float(((unsigned)u) << 16);
}
__device__ inline unsigned short f2bf(float f) {
    unsigned u = __float_as_uint(f);
    u = u + 0x7fff + ((u >> 16) & 1);   // RNE
    return (unsigned short)(u >> 16);
}

// ---------------- CSR build ----------------
__global__ void hist_k(const int* __restrict__ dst, int* __restrict__ counts, int E) {
    int e = blockIdx.x * 256 + threadIdx.x;
    if (e < E) atomicAdd(&counts[dst[e]], 1);
}

__global__ __launch_bounds__(1024) void scanall_k(const int* __restrict__ counts,
                                                  int* __restrict__ row_start,
                                                  int* __restrict__ cursor, int n) {
    __shared__ int tsum[1024];
    int t = threadIdx.x;
    int base = t * 20;
    int s = 0;
#pragma unroll 4
    for (int i = 0; i < 20; i++) {
        int idx = base + i;
        s += (idx < n) ? counts[idx] : 0;
    }
    tsum[t] = s;
    __syncthreads();
    for (int off = 1; off < 1024; off <<= 1) {
        int v = (t >= off) ? tsum[t - off] : 0;
        __syncthreads();
        tsum[t] += v;
        __syncthreads();
    }
    int run = (t == 0) ? 0 : tsum[t - 1];
    for (int i = 0; i < 20; i++) {
        int idx = base + i;
        if (idx < n) {
            row_start[idx] = run;
            cursor[idx] = run;
            run += counts[idx];
        }
    }
}

__global__ void scatter_k(const int* __restrict__ src, const int* __restrict__ dst,
                          const float* __restrict__ w, int* __restrict__ cursor,
                          int2* __restrict__ ep, int E) {
    int e = blockIdx.x * 256 + threadIdx.x;
    if (e < E) {
        int d = dst[e];
        int p = atomicAdd(&cursor[d], 1);
        ep[p] = make_int2(src[e], __float_as_int(w[e]));
    }
}

// ---------------- mega conversion kernel: all weight transposes + gene cast ----------------
__global__ void convall_k(const float* __restrict__ gnn_w, const float* __restrict__ post_w,
                          const float* __restrict__ pin_w, const float* __restrict__ blk_w1,
                          const float* __restrict__ blk_w2, const float* __restrict__ pout_w,
                          const float* __restrict__ gene, unsigned short* __restrict__ gnnT,
                          unsigned short* __restrict__ postT, unsigned short* __restrict__ pinT,
                          unsigned short* __restrict__ w1T, unsigned short* __restrict__ w2T,
                          unsigned short* __restrict__ poutT,
                          unsigned short* __restrict__ geneb) {
    __shared__ float s[32][33];
    int bid = blockIdx.x;
    int tx = threadIdx.x, ty = threadIdx.y;
    const float* W;
    unsigned short* WT;
    int K, N, k0, n0;
    if (bid < 192) {
        int l = bid >> 6, rem = bid & 63;
        W = gnn_w + (size_t)l * GDIM * GDIM;
        WT = gnnT + (size_t)l * GDIM * GDIM;
        K = GDIM; N = GDIM;
        n0 = (rem & 7) * 32; k0 = (rem >> 3) * 32;
    } else if (bid < 256) {
        int rem = bid - 192;
        W = post_w; WT = postT; K = GDIM; N = GDIM;
        n0 = (rem & 7) * 32; k0 = (rem >> 3) * 32;
    } else if (bid < 384) {
        int rem = bid - 256;
        W = pin_w; WT = pinT; K = GDIM; N = HID;
        n0 = (rem & 15) * 32; k0 = (rem >> 4) * 32;
    } else if (bid < 6528) {
        int rem = bid - 384;
        int l = rem >> 10; rem &= 1023;
        W = blk_w1 + (size_t)l * HID * INNER;
        WT = w1T + (size_t)l * HID * INNER;
        K = HID; N = INNER;
        n0 = (rem & 63) * 32; k0 = (rem >> 6) * 32;
    } else if (bid < 12672) {
        int rem = bid - 6528;
        int l = rem >> 10; rem &= 1023;
        W = blk_w2 + (size_t)l * INNER * HID;
        WT = w2T + (size_t)l * INNER * HID;
        K = INNER; N = HID;
        n0 = (rem & 15) * 32; k0 = (rem >> 4) * 32;
    } else if (bid < 13440) {
        int rem = bid - 12672;
        W = pout_w; WT = poutT; K = HID; N = NCLS * RANK;
        n0 = (rem % 48) * 32; k0 = (rem / 48) * 32;
    } else {
        int i8 = (bid - 13440) * 256 + ty * 32 + tx;
        const float4* xp = (const float4*)gene;
        float4 a = xp[i8 * 2], b = xp[i8 * 2 + 1];
        *(ushort4*)(geneb + (size_t)i8 * 8) =
            make_ushort4(f2bf(a.x), f2bf(a.y), f2bf(a.z), f2bf(a.w));
        *(ushort4*)(geneb + (size_t)i8 * 8 + 4) =
            make_ushort4(f2bf(b.x), f2bf(b.y), f2bf(b.z), f2bf(b.w));
        return;
    }
#pragma unroll
    for (int i = 0; i < 4; i++)
        s[ty + 8 * i][tx] = W[(size_t)(k0 + ty + 8 * i) * N + n0 + tx];
    __syncthreads();
#pragma unroll
    for (int i = 0; i < 4; i++)
        WT[(size_t)(n0 + ty + 8 * i) * K + k0 + tx] = f2bf(s[tx][ty + 8 * i]);
}

// ---------------- GNN LayerNorm (D=256), bf16 out ----------------
__global__ void lnb_k(const float* __restrict__ X, const float* __restrict__ sc,
                      const float* __restrict__ bi, unsigned short* __restrict__ Y, int M) {
    int row = blockIdx.x * 4 + (threadIdx.x >> 6);
    int lane = threadIdx.x & 63;
    if (row >= M) return;
    float4 v = ((const float4*)(X + (size_t)row * GDIM))[lane];
    float sum = v.x + v.y + v.z + v.w;
#pragma unroll
    for (int off = 32; off >= 1; off >>= 1) sum += __shfl_xor(sum, off);
    float mu = sum / GDIM;
    float a = v.x - mu, b = v.y - mu, c = v.z - mu, d = v.w - mu;
    float sq = a * a + b * b + c * c + d * d;
#pragma unroll
    for (int off = 32; off >= 1; off >>= 1) sq += __shfl_xor(sq, off);
    float rstd = rsqrtf(sq / GDIM + 1e-5f);
    float4 s4 = ((const float4*)sc)[lane];
    float4 b4 = ((const float4*)bi)[lane];
    *(ushort4*)(Y + (size_t)row * GDIM + lane * 4) =
        make_ushort4(f2bf(a * rstd * s4.x + b4.x), f2bf(b * rstd * s4.y + b4.y),
                     f2bf(c * rstd * s4.z + b4.z), f2bf(d * rstd * s4.w + b4.w));
}

// ---------------- CSR aggregation, 16-deep MLP unroll ----------------
__device__ inline void agg_row(int beg, int cnt, int lane, const int2* __restrict__ ep,
                               const unsigned short* __restrict__ H, float& a0, float& a1,
                               float& a2, float& a3) {
    int t = 0;
    for (; t + 16 <= cnt; t += 16) {
        int2 e[16];
#pragma unroll
        for (int u = 0; u < 16; u++) e[u] = ep[beg + t + u];
        ushort4 v[16];
#pragma unroll
        for (int u = 0; u < 16; u++)
            v[u] = *(const ushort4*)(H + (size_t)e[u].x * GDIM + lane * 4);
#pragma unroll
        for (int u = 0; u < 16; u++) {
            float w = __int_as_float(e[u].y);
            a0 = fmaf(bf2f(v[u].x), w, a0);
            a1 = fmaf(bf2f(v[u].y), w, a1);
            a2 = fmaf(bf2f(v[u].z), w, a2);
            a3 = fmaf(bf2f(v[u].w), w, a3);
        }
    }
    for (; t + 4 <= cnt; t += 4) {
        int2 e[4];
#pragma unroll
        for (int u = 0; u < 4; u++) e[u] = ep[beg + t + u];
        ushort4 v[4];
#pragma unroll
        for (int u = 0; u < 4; u++)
            v[u] = *(const ushort4*)(H + (size_t)e[u].x * GDIM + lane * 4);
#pragma unroll
        for (int u = 0; u < 4; u++) {
            float w = __int_as_float(e[u].y);
            a0 = fmaf(bf2f(v[u].x), w, a0);
            a1 = fmaf(bf2f(v[u].y), w, a1);
            a2 = fmaf(bf2f(v[u].z), w, a2);
            a3 = fmaf(bf2f(v[u].w), w, a3);
        }
    }
    for (; t < cnt; t++) {
        int2 e = ep[beg + t];
        float w = __int_as_float(e.y);
        ushort4 v = *(const ushort4*)(H + (size_t)e.x * GDIM + lane * 4);
        a0 = fmaf(bf2f(v.x), w, a0);
        a1 = fmaf(bf2f(v.y), w, a1);
        a2 = fmaf(bf2f(v.z), w, a2);
        a3 = fmaf(bf2f(v.w), w, a3);
    }
}

__global__ void aggb_k(const int* __restrict__ row_start, const int* __restrict__ counts,
                       const int2* __restrict__ ep, const unsigned short* __restrict__ H,
                       unsigned short* __restrict__ AGG, int n) {
    int row = blockIdx.x * 4 + (threadIdx.x >> 6);
    int lane = threadIdx.x & 63;
    if (row >= n) return;
    float a0 = 0.f, a1 = 0.f, a2 = 0.f, a3 = 0.f;
    agg_row(row_start[row], counts[row], lane, ep, H, a0, a1, a2, a3);
    *(ushort4*)(AGG + (size_t)row * GDIM + lane * 4) =
        make_ushort4(f2bf(a0), f2bf(a1), f2bf(a2), f2bf(a3));
}

__global__ void aggsel_k(const int* __restrict__ idx, const int* __restrict__ row_start,
                         const int* __restrict__ counts, const int2* __restrict__ ep,
                         const unsigned short* __restrict__ H, unsigned short* __restrict__ AGG) {
    int b = blockIdx.x * 4 + (threadIdx.x >> 6);
    int lane = threadIdx.x & 63;
    int id = idx[b];
    int row = id < 0 ? 0 : id;
    float a0 = 0.f, a1 = 0.f, a2 = 0.f, a3 = 0.f;
    agg_row(row_start[row], counts[row], lane, ep, H, a0, a1, a2, a3);
    *(ushort4*)(AGG + (size_t)b * GDIM + lane * 4) =
        make_ushort4(f2bf(a0), f2bf(a1), f2bf(a2), f2bf(a3));
}

// ---------------- bf16 MFMA GEMM 128x128 (GNN layers, logits) ----------------
template <int ACT, bool RES, bool BIAS>
__global__ __launch_bounds__(256) void mgemm_k(const unsigned short* __restrict__ A,
                                               const unsigned short* __restrict__ BT,
                                               const float* __restrict__ bias,
                                               const float* __restrict__ R,
                                               float* __restrict__ C, int M, int N, int K) {
    __shared__ unsigned short As[128 * 32];
    __shared__ unsigned short Bs[128 * 32];
    int m0 = blockIdx.y * 128, n0 = blockIdx.x * 128;
    int tid = threadIdx.x;
    int wave = tid >> 6, lane = tid & 63;
    int wm = (wave >> 1) * 64, wn = (wave & 1) * 64;
    int lrow = lane & 15, lq = lane >> 4;

    f32x4 acc[4][4];
    const f32x4 zz = {0.f, 0.f, 0.f, 0.f};
#pragma unroll
    for (int i = 0; i < 4; i++)
#pragma unroll
        for (int j = 0; j < 4; j++) acc[i][j] = zz;

    int r0 = tid >> 2;
    int q = tid & 3;

    for (int k0 = 0; k0 < K; k0 += 32) {
#pragma unroll
        for (int p = 0; p < 2; p++) {
            int row = r0 + p * 64;
            int gm = m0 + row;
            uint4 va = make_uint4(0, 0, 0, 0);
            if (gm < M) va = *(const uint4*)(A + (size_t)gm * K + k0 + q * 8);
            *(uint4*)&As[row * 32 + q * 8] = va;
            int gn = n0 + row;
            uint4 vb = make_uint4(0, 0, 0, 0);
            if (gn < N) vb = *(const uint4*)(BT + (size_t)gn * K + k0 + q * 8);
            *(uint4*)&Bs[row * 32 + q * 8] = vb;
        }
        __syncthreads();
        bf16x8 af[4], bfr[4];
#pragma unroll
        for (int i = 0; i < 4; i++)
            af[i] = *(const bf16x8*)&As[(wm + i * 16 + lrow) * 32 + lq * 8];
#pragma unroll
        for (int j = 0; j < 4; j++)
            bfr[j] = *(const bf16x8*)&Bs[(wn + j * 16 + lrow) * 32 + lq * 8];
#pragma unroll
        for (int i = 0; i < 4; i++)
#pragma unroll
            for (int j = 0; j < 4; j++)
                acc[i][j] =
                    __builtin_amdgcn_mfma_f32_16x16x32_bf16(af[i], bfr[j], acc[i][j], 0, 0, 0);
        __syncthreads();
    }

#pragma unroll
    for (int i = 0; i < 4; i++) {
#pragma unroll
        for (int j = 0; j < 4; j++) {
            int gn = n0 + wn + j * 16 + lrow;
            if (gn >= N) continue;
            float bv = BIAS ? bias[gn] : 0.f;
#pragma unroll
            for (int r = 0; r < 4; r++) {
                int gm = m0 + wm + i * 16 + lq * 4 + r;
                if (gm >= M) continue;
                float v = acc[i][j][r] + bv;
                if (ACT == 1) v = fmaxf(v, 0.f);
                if (RES) v += R[(size_t)gm * N + gn];
                C[(size_t)gm * N + gn] = v;
            }
        }
    }
}

// ---------------- bf16 MFMA full-K, bf16 out, fused epilogue (small GEMMs) ----------------
// 64x64 tile, 4 waves stacked in M. ACT: 0 none, 1 relu, 2 gelu.
// EPI: 0 plain, 1 OOV-replace (aux=oov_emb), 2 indexed-residual (aux=R [NNODES x N]).
template <int ACT, int EPI>
__global__ __launch_bounds__(256) void mfull_k(const unsigned short* __restrict__ A,
                                               const unsigned short* __restrict__ BT,
                                               const float* __restrict__ bias,
                                               const int* __restrict__ idx,
                                               const float* __restrict__ aux,
                                               unsigned short* __restrict__ O, int M, int N,
                                               int K) {
    __shared__ unsigned short As[64 * 32];
    __shared__ unsigned short Bs[64 * 32];
    int m0 = blockIdx.y * 64, n0 = blockIdx.x * 64;
    int tid = threadIdx.x;
    int wave = tid >> 6, lane = tid & 63;
    int wm = wave * 16;
    int lrow = lane & 15, lq = lane >> 4;
    f32x4 acc[4];
    const f32x4 zz = {0.f, 0.f, 0.f, 0.f};
#pragma unroll
    for (int j = 0; j < 4; j++) acc[j] = zz;
    int r0 = tid >> 2;
    int q = tid & 3;
    for (int k0 = 0; k0 < K; k0 += 32) {
        *(uint4*)&As[r0 * 32 + q * 8] = *(const uint4*)(A + (size_t)(m0 + r0) * K + k0 + q * 8);
        *(uint4*)&Bs[r0 * 32 + q * 8] = *(const uint4*)(BT + (size_t)(n0 + r0) * K + k0 + q * 8);
        __syncthreads();
        bf16x8 af = *(const bf16x8*)&As[(wm + lrow) * 32 + lq * 8];
#pragma unroll
        for (int j = 0; j < 4; j++) {
            bf16x8 bfr = *(const bf16x8*)&Bs[(j * 16 + lrow) * 32 + lq * 8];
            acc[j] = __builtin_amdgcn_mfma_f32_16x16x32_bf16(af, bfr, acc[j], 0, 0, 0);
        }
        __syncthreads();
    }
#pragma unroll
    for (int j = 0; j < 4; j++) {
        int gn = n0 + j * 16 + lrow;
        float bv = bias[gn];
#pragma unroll
        for (int r = 0; r < 4; r++) {
            int gm = m0 + wm + lq * 4 + r;
            float v = acc[j][r] + bv;
            if (ACT == 1) v = fmaxf(v, 0.f);
            if (ACT == 2) v = 0.5f * v * (1.f + erff(v * 0.70710678118654752f));
            if (EPI == 2) {
                int id = idx[gm];
                int safe = id < 0 ? 0 : id;
                v += aux[(size_t)safe * N + gn];
            }
            if (EPI == 1) {
                if (idx[gm] < 0) v = aux[gn];
            }
            O[(size_t)gm * N + gn] = f2bf(v);
        }
    }
}

// ---------------- bf16 MFMA split-K phase 1: 64x64 tile, fp32 partials ----------------
__global__ __launch_bounds__(256) void msk_k(const unsigned short* __restrict__ A,
                                             const unsigned short* __restrict__ BT,
                                             float* __restrict__ Cp, int M, int N, int K,
                                             int kchunk) {
    __shared__ unsigned short As[64 * 32];
    __shared__ unsigned short Bs[64 * 32];
    int m0 = blockIdx.y * 64, n0 = blockIdx.x * 64;
    int kbeg = blockIdx.z * kchunk;
    float* C = Cp + (size_t)blockIdx.z * M * N;
    int tid = threadIdx.x;
    int wave = tid >> 6, lane = tid & 63;
    int wm = wave * 16;
    int lrow = lane & 15, lq = lane >> 4;
    f32x4 acc[4];
    const f32x4 zz = {0.f, 0.f, 0.f, 0.f};
#pragma unroll
    for (int j = 0; j < 4; j++) acc[j] = zz;
    int r0 = tid >> 2;
    int q = tid & 3;
    for (int k0 = kbeg; k0 < kbeg + kchunk; k0 += 32) {
        *(uint4*)&As[r0 * 32 + q * 8] = *(const uint4*)(A + (size_t)(m0 + r0) * K + k0 + q * 8);
        *(uint4*)&Bs[r0 * 32 + q * 8] = *(const uint4*)(BT + (size_t)(n0 + r0) * K + k0 + q * 8);
        __syncthreads();
        bf16x8 af = *(const bf16x8*)&As[(wm + lrow) * 32 + lq * 8];
#pragma unroll
        for (int j = 0; j < 4; j++) {
            bf16x8 bfr = *(const bf16x8*)&Bs[(j * 16 + lrow) * 32 + lq * 8];
            acc[j] = __builtin_amdgcn_mfma_f32_16x16x32_bf16(af, bfr, acc[j], 0, 0, 0);
        }
        __syncthreads();
    }
#pragma unroll
    for (int j = 0; j < 4; j++) {
        int gn = n0 + j * 16 + lrow;
#pragma unroll
        for (int r = 0; r < 4; r++) {
            int gm = m0 + wm + lq * 4 + r;
            C[(size_t)gm * N + gn] = acc[j][r];
        }
    }
}

// ---------------- fused reducer (head, M=256, N=512) ----------------
template <bool RESID, bool DO_LN>
__global__ void redln_k(const float* __restrict__ Cp, const float* __restrict__ bias,
                        const float* __restrict__ ln_s, const float* __restrict__ ln_b,
                        float* __restrict__ hbuf, unsigned short* __restrict__ outbf, int S) {
    int row = blockIdx.x * 4 + (threadIdx.x >> 6);
    int lane = threadIdx.x & 63;
    float4 a0 = {0.f, 0.f, 0.f, 0.f}, a1 = a0;
    for (int s = 0; s < S; s++) {
        const float4* pp = (const float4*)(Cp + ((size_t)s * BSZ + row) * HID);
        float4 b0 = pp[lane * 2], b1 = pp[lane * 2 + 1];
        a0.x += b0.x; a0.y += b0.y; a0.z += b0.z; a0.w += b0.w;
        a1.x += b1.x; a1.y += b1.y; a1.z += b1.z; a1.w += b1.w;
    }
    const float4* bb = (const float4*)bias;
    float4 c0 = bb[lane * 2], c1 = bb[lane * 2 + 1];
    a0.x += c0.x; a0.y += c0.y; a0.z += c0.z; a0.w += c0.w;
    a1.x += c1.x; a1.y += c1.y; a1.z += c1.z; a1.w += c1.w;
    float4* hp = (float4*)(hbuf + (size_t)row * HID);
    if (RESID) {
        float4 r0 = hp[lane * 2], r1 = hp[lane * 2 + 1];
        a0.x += r0.x; a0.y += r0.y; a0.z += r0.z; a0.w += r0.w;
        a1.x += r1.x; a1.y += r1.y; a1.z += r1.z; a1.w += r1.w;
    }
    hp[lane * 2] = a0;
    hp[lane * 2 + 1] = a1;
    unsigned short* op = outbf + (size_t)row * HID;
    if (DO_LN) {
        float sum = a0.x + a0.y + a0.z + a0.w + a1.x + a1.y + a1.z + a1.w;
#pragma unroll
        for (int off = 32; off >= 1; off >>= 1) sum += __shfl_xor(sum, off);
        float mu = sum / HID;
        float d0 = a0.x - mu, d1 = a0.y - mu, d2 = a0.z - mu, d3 = a0.w - mu;
        float d4 = a1.x - mu, d5 = a1.y - mu, d6 = a1.z - mu, d7 = a1.w - mu;
        float sq = d0 * d0 + d1 * d1 + d2 * d2 + d3 * d3 + d4 * d4 + d5 * d5 + d6 * d6 + d7 * d7;
#pragma unroll
        for (int off = 32; off >= 1; off >>= 1) sq += __shfl_xor(sq, off);
        float rstd = rsqrtf(sq / HID + 1e-5f);
        const float4* sp = (const float4*)ln_s;
        const float4* bp = (const float4*)ln_b;
        float4 s0 = sp[lane * 2], s1 = sp[lane * 2 + 1];
        float4 t0 = bp[lane * 2], t1 = bp[lane * 2 + 1];
        *(ushort4*)(op + lane * 8) =
            make_ushort4(f2bf(d0 * rstd * s0.x + t0.x), f2bf(d1 * rstd * s0.y + t0.y),
                         f2bf(d2 * rstd * s0.z + t0.z), f2bf(d3 * rstd * s0.w + t0.w));
        *(ushort4*)(op + lane * 8 + 4) =
            make_ushort4(f2bf(d4 * rstd * s1.x + t1.x), f2bf(d5 * rstd * s1.y + t1.y),
                         f2bf(d6 * rstd * s1.z + t1.z), f2bf(d7 * rstd * s1.w + t1.w));
    } else {
        *(ushort4*)(op + lane * 8) = make_ushort4(f2bf(a0.x), f2bf(a0.y), f2bf(a0.z), f2bf(a0.w));
        *(ushort4*)(op + lane * 8 + 4) =
            make_ushort4(f2bf(a1.x), f2bf(a1.y), f2bf(a1.z), f2bf(a1.w));
    }
}

// ---------------- launch ----------------
extern "C" void kernel_launch(void* const* d_in, const int* in_sizes, int n_in,
                              void* d_out, int out_size, void* d_ws, size_t ws_size,
                              hipStream_t stream) {
    const int* node_indices = (const int*)d_in[0];
    const int* edge_src = (const int*)d_in[1];
    const int* edge_dst = edge_src + NEDGES;
    const float* edge_w = (const float*)d_in[2];
    const float* partial_emb = (const float*)d_in[3];
    const float* oov_emb = (const float*)d_in[4];
    const float* gnn_ln_s = (const float*)d_in[5];
    const float* gnn_ln_b = (const float*)d_in[6];
    const float* gnn_w = (const float*)d_in[7];
    const float* gnn_b = (const float*)d_in[8];
    const float* post_w = (const float*)d_in[9];
    const float* post_b = (const float*)d_in[10];
    const float* pin_w = (const float*)d_in[11];
    const float* pin_b = (const float*)d_in[12];
    const float* blk_ln_s = (const float*)d_in[13];
    const float* blk_ln_b = (const float*)d_in[14];
    const float* blk_w1 = (const float*)d_in[15];
    const float* blk_b1 = (const float*)d_in[16];
    const float* blk_w2 = (const float*)d_in[17];
    const float* blk_b2 = (const float*)d_in[18];
    const float* pout_w = (const float*)d_in[19];
    const float* pout_b = (const float*)d_in[20];
    const float* gene = (const float*)d_in[21];
    float* out = (float*)d_out;

    char* p = (char*)d_ws;
    auto alloc = [&](size_t bytes) {
        char* r = p;
        p += (bytes + 255) & ~(size_t)255;
        return r;
    };
    int* counts = (int*)alloc(NNODES * 4);
    int* row_start = (int*)alloc(NNODES * 4);
    int* cursor = (int*)alloc(NNODES * 4);
    int2* epack = (int2*)alloc((size_t)NEDGES * 8);
    // 'part': GNN phase = ln_bf + aggbf (bf16); head phase = split-K fp32 partials
    float* part = (float*)alloc((size_t)NNODES * GDIM * 4);
    unsigned short* ln_bf = (unsigned short*)part;
    unsigned short* aggbf = (unsigned short*)((char*)part + (size_t)NNODES * GDIM * 2);
    float* xa = (float*)alloc((size_t)NNODES * GDIM * 4);
    float* xb = (float*)alloc((size_t)NNODES * GDIM * 4);
    float* hbuf = (float*)alloc((size_t)BSZ * HID * 4);
    unsigned short* aggselb = (unsigned short*)alloc((size_t)BSZ * GDIM * 2);
    unsigned short* pertinbf = (unsigned short*)alloc((size_t)BSZ * GDIM * 2);
    unsigned short* pertbf = (unsigned short*)alloc((size_t)BSZ * GDIM * 2);
    unsigned short* zlnbf = (unsigned short*)alloc((size_t)BSZ * HID * 2);
    unsigned short* z1bf = (unsigned short*)alloc((size_t)BSZ * INNER * 2);
    unsigned short* hbufbf = (unsigned short*)alloc((size_t)BSZ * HID * 2);
    unsigned short* projb = (unsigned short*)alloc((size_t)BSZ * NCLS * RANK * 2);
    unsigned short* gnnT = (unsigned short*)alloc((size_t)3 * GDIM * GDIM * 2);
    unsigned short* postT = (unsigned short*)alloc((size_t)GDIM * GDIM * 2);
    unsigned short* pinT = (unsigned short*)alloc((size_t)HID * GDIM * 2);
    unsigned short* w1T = (unsigned short*)alloc((size_t)6 * INNER * HID * 2);
    unsigned short* w2T = (unsigned short*)alloc((size_t)6 * HID * INNER * 2);
    unsigned short* poutT = (unsigned short*)alloc((size_t)NCLS * RANK * HID * 2);
    unsigned short* geneb = (unsigned short*)alloc((size_t)NGENES * RANK * 2);

    const int EB = (NEDGES + 255) / 256;

    hipMemsetAsync(counts, 0, NNODES * 4, stream);
    convall_k<<<15100, dim3(32, 8), 0, stream>>>(gnn_w, post_w, pin_w, blk_w1, blk_w2, pout_w,
                                                 gene, gnnT, postT, pinT, w1T, w2T, poutT, geneb);

    // CSR build
    hist_k<<<EB, 256, 0, stream>>>(edge_dst, counts, NEDGES);
    scanall_k<<<1, 1024, 0, stream>>>(counts, row_start, cursor, NNODES);
    scatter_k<<<EB, 256, 0, stream>>>(edge_src, edge_dst, edge_w, cursor, epack, NEDGES);

    // GNN layers 1 & 2 (full graph), layer 3 selective
    const float* x_in = partial_emb;
    float* bufs[2] = {xa, xb};
    for (int i = 0; i < 2; i++) {
        lnb_k<<<(NNODES + 3) / 4, 256, 0, stream>>>(x_in, gnn_ln_s + i * GDIM,
                                                    gnn_ln_b + i * GDIM, ln_bf, NNODES);
        aggb_k<<<(NNODES + 3) / 4, 256, 0, stream>>>(row_start, counts, epack, ln_bf, aggbf,
                                                     NNODES);
        float* x_out = bufs[i];
        mgemm_k<1, true, true><<<dim3(GDIM / 128, (NNODES + 127) / 128), 256, 0, stream>>>(
            aggbf, gnnT + (size_t)i * GDIM * GDIM, gnn_b + i * GDIM, x_in, x_out, NNODES, GDIM,
            GDIM);
        x_in = x_out;
    }
    lnb_k<<<(NNODES + 3) / 4, 256, 0, stream>>>(xb, gnn_ln_s + 2 * GDIM, gnn_ln_b + 2 * GDIM,
                                                ln_bf, NNODES);
    aggsel_k<<<BSZ / 4, 256, 0, stream>>>(node_indices, row_start, counts, epack, ln_bf, aggselb);
    mfull_k<1, 2><<<dim3(GDIM / 64, BSZ / 64), 256, 0, stream>>>(
        aggselb, gnnT + (size_t)2 * GDIM * GDIM, gnn_b + 2 * GDIM, node_indices, xb, pertinbf,
        BSZ, GDIM, GDIM);

    // post_mp + OOV replace
    mfull_k<0, 1><<<dim3(GDIM / 64, BSZ / 64), 256, 0, stream>>>(
        pertinbf, postT, post_b, node_indices, oov_emb, pertbf, BSZ, GDIM, GDIM);

    // pin (split-K S=4 + fused reduce/LN)
    msk_k<<<dim3(HID / 64, BSZ / 64, 4), 256, 0, stream>>>(pertbf, pinT, part, BSZ, HID, GDIM,
                                                           GDIM / 4);
    redln_k<false, true><<<BSZ / 4, 256, 0, stream>>>(part, pin_b, blk_ln_s, blk_ln_b, hbuf,
                                                      zlnbf, 4);

    // 6 head blocks
    for (int i = 0; i < 6; i++) {
        mfull_k<2, 0><<<dim3(INNER / 64, BSZ / 64), 256, 0, stream>>>(
            zlnbf, w1T + (size_t)i * INNER * HID, blk_b1 + i * INNER, nullptr, nullptr, z1bf, BSZ,
            INNER, HID);
        msk_k<<<dim3(HID / 64, BSZ / 64, 8), 256, 0, stream>>>(
            z1bf, w2T + (size_t)i * HID * INNER, part, BSZ, HID, INNER, INNER / 8);
        if (i < 5) {
            redln_k<true, true><<<BSZ / 4, 256, 0, stream>>>(
                part, blk_b2 + i * HID, blk_ln_s + (i + 1) * HID, blk_ln_b + (i + 1) * HID, hbuf,
                zlnbf, 8);
        } else {
            redln_k<true, false><<<BSZ / 4, 256, 0, stream>>>(part, blk_b2 + i * HID, nullptr,
                                                              nullptr, hbuf, hbufbf, 8);
        }
    }

    // pout
    mfull_k<0, 0><<<dim3((NCLS * RANK) / 64, BSZ / 64), 256, 0, stream>>>(
        hbufbf, poutT, pout_b, nullptr, nullptr, projb, BSZ, NCLS * RANK, HID);

    // logits
    mgemm_k<0, false, false><<<dim3((NGENES + 127) / 128, (BSZ * NCLS) / 128), 256, 0, stream>>>(
        projb, geneb, nullptr, nullptr, out, BSZ * NCLS, NGENES, RANK);
}